// Round 10
// baseline (9941.315 us; speedup 1.0000x reference)
//
#include <hip/hip_runtime.h>

#define NPTS 32768
#define NB 8
#define NG 256

// ---------------- K1: FPS (numpy f32 elementwise, noFMA) ----------------
__global__ __launch_bounds__(1024) void k_fps(const float* __restrict__ pts,
                                              float* __restrict__ ptsg,
                                              float* __restrict__ distg) {
  const int b = blockIdx.x;
  const int t = threadIdx.x;
  const float* __restrict__ P = pts + (size_t)b * NPTS * 3;
  float* __restrict__ D = distg + (size_t)b * NPTS;
  float cx[32], cy[32], cz[32];
#pragma unroll
  for (int i = 0; i < 32; ++i) {
    int p = i * 1024 + t;
    cx[i] = P[p * 3 + 0];
    cy[i] = P[p * 3 + 1];
    cz[i] = P[p * 3 + 2];
  }
  __shared__ float rv[16];
  __shared__ int ri[16];
  __shared__ int scur;
  int cur = 0;
  for (int it = 0; it < NG; ++it) {
    float sx = P[cur * 3 + 0], sy = P[cur * 3 + 1], sz = P[cur * 3 + 2];
    if (t == 0) {
      float* G = ptsg + ((size_t)b * NG + it) * 3;
      G[0] = sx; G[1] = sy; G[2] = sz;
    }
    float bv = -1.0f;
    int bi = 0x7fffffff;
#pragma unroll
    for (int i = 0; i < 32; ++i) {
      int p = i * 1024 + t;
      float dx = __fsub_rn(cx[i], sx), dy = __fsub_rn(cy[i], sy), dz = __fsub_rn(cz[i], sz);
      float d = __fadd_rn(__fadd_rn(__fmul_rn(dx, dx), __fmul_rn(dy, dy)),
                          __fmul_rn(dz, dz));
      float nd = d;
      if (it > 0) nd = fminf(D[p], d);
      D[p] = nd;
      if (nd > bv || (nd == bv && p < bi)) { bv = nd; bi = p; }
    }
    for (int off = 32; off > 0; off >>= 1) {
      float ov = __shfl_down(bv, off);
      int oi = __shfl_down(bi, off);
      if (ov > bv || (ov == bv && oi < bi)) { bv = ov; bi = oi; }
    }
    int wid = t >> 6, lane = t & 63;
    if (lane == 0) { rv[wid] = bv; ri[wid] = bi; }
    __syncthreads();
    if (t == 0) {
      float v = rv[0]; int ix = ri[0];
      for (int w = 1; w < 16; ++w)
        if (rv[w] > v || (rv[w] == v && ri[w] < ix)) { v = rv[w]; ix = ri[w]; }
      scur = ix;
    }
    __syncthreads();
    cur = scur;
  }
}

// ------ K2: G2SD encoder layer 1 — f32 BLAS-style (seq FMA over K=3) ------
__global__ __launch_bounds__(256) void k_enc1(const float* __restrict__ ptsg,
                                              const float* __restrict__ w1,
                                              const float* __restrict__ b1,
                                              float* __restrict__ h1) {
  int gid = blockIdx.x * 256 + threadIdx.x;
  int f = gid & 127;
  int p = gid >> 7;
  const float* x = ptsg + (size_t)p * 3;
  float acc = __fmul_rn(x[0], w1[0 * 128 + f]);
  acc = fmaf(x[1], w1[1 * 128 + f], acc);
  acc = fmaf(x[2], w1[2 * 128 + f], acc);
  h1[gid] = fmaxf(__fadd_rn(acc, b1[f]), 0.0f);
}

// --- K3: G2SD enc layer 2 + maxpool — f32 seq-FMA over K=128, relu, max ---
__global__ __launch_bounds__(256) void k_code(const float* __restrict__ h1,
                                              const float* __restrict__ w2,
                                              const float* __restrict__ b2,
                                              float* __restrict__ codeG) {
  int b = blockIdx.x;
  int j = threadIdx.x;  // feature 0..255
  float m = -__builtin_inff();
  for (int p = 0; p < 256; ++p) {
    const float* hrow = h1 + ((size_t)b * 256 + p) * 128;
    float acc = __fmul_rn(hrow[0], w2[0 * 256 + j]);
    for (int f = 1; f < 128; ++f)
      acc = fmaf(hrow[f], w2[f * 256 + j], acc);
    float v = fmaxf(__fadd_rn(acc, b2[j]), 0.0f);
    m = fmaxf(m, v);
  }
  codeG[b * 256 + j] = m;
}

// ---- K4: G2SD decoder — f32 seq-FMA (K=258 then K=256), BLAS order -------
__global__ __launch_bounds__(256) void k_dec(const float* __restrict__ codeG,
                                             const float* __restrict__ w1,
                                             const float* __restrict__ b1,
                                             const float* __restrict__ w2,
                                             const float* __restrict__ b2,
                                             float* __restrict__ recg) {
  int blk = blockIdx.x;
  int b = blk >> 8, g = blk & 255;
  int f = threadIdx.x;
  float gx = (float)((((double)(g & 15)) + 0.5) / 16.0);
  float gy = (float)((((double)(g >> 4)) + 0.5) / 16.0);
  const float* code = codeG + b * 256;
  float acc = __fmul_rn(gx, w1[0 * 256 + f]);
  acc = fmaf(gy, w1[1 * 256 + f], acc);
  for (int c = 0; c < 256; ++c)
    acc = fmaf(code[c], w1[(2 + c) * 256 + f], acc);
  float a = fmaxf(__fadd_rn(acc, b1[f]), 0.0f);
  __shared__ float hs[256];
  hs[f] = a;
  __syncthreads();
  if (f < 3) {
    float acc2 = __fmul_rn(hs[0], w2[0 * 3 + f]);
    for (int k = 1; k < 256; ++k)
      acc2 = fmaf(hs[k], w2[k * 3 + f], acc2);
    recg[blk * 3 + f] = __fadd_rn(acc2, b2[f]);
  }
}

// -------- K5: BRUTE-FORCE exact stable KNN-64 ------------------------------
// Keys match np-f32 _sqdist: ra/rb = materialized-square noFMA seq sums;
// ab = einsum -> FMA chain; d = (ra+rb) - 2*ab.
__global__ __launch_bounds__(1024) void k_knn_bf(const float* __restrict__ pts,
                                                 const float* __restrict__ recg,
                                                 float* __restrict__ ptsc) {
  int bg = blockIdx.x;
  int b = bg >> 8;
  int t = threadIdx.x;
  const float* __restrict__ P = pts + (size_t)b * NPTS * 3;
  float qx = recg[bg * 3 + 0];
  float qy = recg[bg * 3 + 1];
  float qz = recg[bg * 3 + 2];
  float ra = __fadd_rn(__fadd_rn(__fmul_rn(qx, qx), __fmul_rn(qy, qy)),
                       __fmul_rn(qz, qz));
  float kk[32];
#pragma unroll
  for (int i = 0; i < 32; ++i) {
    int p = i * 1024 + t;
    float px = P[p * 3], py = P[p * 3 + 1], pz = P[p * 3 + 2];
    float rb = __fadd_rn(__fadd_rn(__fmul_rn(px, px), __fmul_rn(py, py)),
                         __fmul_rn(pz, pz));
    float ab = fmaf(qz, pz, fmaf(qy, py, __fmul_rn(qx, px)));  // einsum FMA chain
    kk[i] = __fsub_rn(__fadd_rn(ra, rb), __fmul_rn(2.0f, ab));
  }
  __shared__ float skey[16];
  __shared__ int sidx[16];
  __shared__ float s_pk;
  __shared__ int s_pi;
  float prevK = -__builtin_inff();
  int prevI = -1;
  for (int r = 0; r < 64; ++r) {
    float bk = __builtin_inff();
    int bi = 0x7fffffff;
#pragma unroll
    for (int i = 0; i < 32; ++i) {
      int p = i * 1024 + t;
      float k = kk[i];
      bool gt = (k > prevK) || (k == prevK && p > prevI);
      if (gt && (k < bk || (k == bk && p < bi))) { bk = k; bi = p; }
    }
    for (int off = 32; off > 0; off >>= 1) {
      float ok = __shfl_down(bk, off);
      int oi = __shfl_down(bi, off);
      if (ok < bk || (ok == bk && oi < bi)) { bk = ok; bi = oi; }
    }
    int wid = t >> 6, lane = t & 63;
    if (lane == 0) { skey[wid] = bk; sidx[wid] = bi; }
    __syncthreads();
    if (t == 0) {
      float wk = skey[0]; int wi = sidx[0];
      for (int w = 1; w < 16; ++w)
        if (skey[w] < wk || (skey[w] == wk && sidx[w] < wi)) {
          wk = skey[w]; wi = sidx[w];
        }
      s_pk = wk; s_pi = wi;
      float* o = ptsc + ((size_t)bg * 64 + r) * 3;
      o[0] = P[wi * 3]; o[1] = P[wi * 3 + 1]; o[2] = P[wi * 3 + 2];
    }
    __syncthreads();
    prevK = s_pk;
    prevI = s_pi;
  }
}

// ---- K6: patch normalize + S2PF + rescale + resample — all f32 BLAS-style --
__device__ inline float wmaxf(float v) {
  for (int off = 1; off < 64; off <<= 1) v = fmaxf(v, __shfl_xor(v, off));
  return v;
}
__device__ inline float wminf(float v) {
  for (int off = 1; off < 64; off <<= 1) v = fminf(v, __shfl_xor(v, off));
  return v;
}

__global__ __launch_bounds__(64) void k_patch(const float* __restrict__ ptsc,
                                              const float* __restrict__ se_w1,
                                              const float* __restrict__ se_b1,
                                              const float* __restrict__ sd_w1,
                                              const float* __restrict__ sd_b1,
                                              const float* __restrict__ sd_w2,
                                              const float* __restrict__ sd_b2,
                                              float* __restrict__ out) {
  int bg = blockIdx.x;
  int b = bg >> 8, g = bg & 255;
  int j = threadIdx.x;
  __shared__ float pc[64][3];
  __shared__ float xn[64][3];
  __shared__ float code[128];
  __shared__ float cmean[3];
  __shared__ float earr[64][2];
  const float* src = ptsc + ((size_t)bg * 64 + j) * 3;
  float p0 = src[0], p1 = src[1], p2 = src[2];
  pc[j][0] = p0; pc[j][1] = p1; pc[j][2] = p2;
  __syncthreads();
  // np.mean over STRIDED axis (64 slots, inner SIMD dim = 3 contiguous):
  // plain SEQUENTIAL accumulation k=0..63 (pairwise only for contiguous axes)
  if (j < 3) {
    float sum = pc[0][j];
    for (int k = 1; k < 64; ++k) sum = __fadd_rn(sum, pc[k][j]);
    cmean[j] = __fdiv_rn(sum, 64.0f);
  }
  __syncthreads();
  float x0 = __fsub_rn(p0, cmean[0]);
  float x1 = __fsub_rn(p1, cmean[1]);
  float x2 = __fsub_rn(p2, cmean[2]);
  float nr = sqrtf(__fadd_rn(__fadd_rn(__fmul_rn(x0, x0), __fmul_rn(x1, x1)),
                             __fmul_rn(x2, x2)));
  float s = wmaxf(nr);
  float den = __fadd_rn(s, 1e-8f);
  x0 = __fdiv_rn(x0, den);
  x1 = __fdiv_rn(x1, den);
  x2 = __fdiv_rn(x2, den);
  xn[j][0] = x0; xn[j][1] = x1; xn[j][2] = x2;
  __syncthreads();
  // per-point encoder (K=3, seq FMA) + relu + maxpool -> code[128]
  for (int ff = 0; ff < 2; ++ff) {
    int f = j + ff * 64;
    float w0 = se_w1[0 * 128 + f];
    float w1v = se_w1[1 * 128 + f];
    float w2v = se_w1[2 * 128 + f];
    float bb = se_b1[f];
    float m = -__builtin_inff();
    for (int p = 0; p < 64; ++p) {
      float acc = __fmul_rn(xn[p][0], w0);
      acc = fmaf(xn[p][1], w1v, acc);
      acc = fmaf(xn[p][2], w2v, acc);
      float v = fmaxf(__fadd_rn(acc, bb), 0.0f);
      m = fmaxf(m, v);
    }
    code[f] = m;
  }
  __syncthreads();
  // sd layer1 (K=131: x then code, seq FMA) -> relu -> layer2 (K=128 seq FMA)
  float pe0 = 0.0f, pe1 = 0.0f;
  for (int f = 0; f < 128; ++f) {
    float acc = __fmul_rn(x0, sd_w1[0 * 128 + f]);
    acc = fmaf(x1, sd_w1[1 * 128 + f], acc);
    acc = fmaf(x2, sd_w1[2 * 128 + f], acc);
    for (int c = 0; c < 128; ++c)
      acc = fmaf(code[c], sd_w1[(3 + c) * 128 + f], acc);
    float h = fmaxf(__fadd_rn(acc, sd_b1[f]), 0.0f);
    if (f == 0) {
      pe0 = __fmul_rn(h, sd_w2[0 * 2 + 0]);
      pe1 = __fmul_rn(h, sd_w2[0 * 2 + 1]);
    } else {
      pe0 = fmaf(h, sd_w2[f * 2 + 0], pe0);
      pe1 = fmaf(h, sd_w2[f * 2 + 1], pe1);
    }
  }
  pe0 = __fadd_rn(pe0, sd_b2[0]);
  pe1 = __fadd_rn(pe1, sd_b2[1]);
  // rescale_pe, numpy elementwise op order, f32
  float mn0 = wminf(pe0), mx0 = wmaxf(pe0);
  float mn1 = wminf(pe1), mx1 = wmaxf(pe1);
  const float SPAN = (float)0.999998;
  float e0 = __fadd_rn(__fmul_rn(__fdiv_rn(__fsub_rn(pe0, mn0),
                                           __fadd_rn(__fsub_rn(mx0, mn0), 1e-8f)),
                                 SPAN), 1e-6f);
  float e1 = __fadd_rn(__fmul_rn(__fdiv_rn(__fsub_rn(pe1, mn1),
                                           __fadd_rn(__fsub_rn(mx1, mn1), 1e-8f)),
                                 SPAN), 1e-6f);
  earr[j][0] = e0;
  earr[j][1] = e1;
  __syncthreads();
  // serial per-cell argmin (np.argmin first-occurrence, f32 noFMA)
  if (j < 16) {
    float gxf = (float)((((double)(j & 3)) + 0.5) * 0.25);
    float gyf = (float)((((double)(j >> 2)) + 0.5) * 0.25);
    float best = __builtin_inff();
    int bi = 0;
    for (int sslot = 0; sslot < 64; ++sslot) {
      float dx = __fsub_rn(gxf, earr[sslot][0]);
      float dy = __fsub_rn(gyf, earr[sslot][1]);
      float d2 = __fadd_rn(__fmul_rn(dx, dx), __fmul_rn(dy, dy));
      if (d2 < best) { best = d2; bi = sslot; }
    }
    int rr = (g >> 4) * 4 + (j >> 2);
    int cc = (g & 15) * 4 + (j & 3);
    float* o = out + (((size_t)b * 4096) + (size_t)(rr * 64 + cc)) * 3;
    o[0] = pc[bi][0]; o[1] = pc[bi][1]; o[2] = pc[bi][2];
  }
}

extern "C" void kernel_launch(void* const* d_in, const int* in_sizes, int n_in,
                              void* d_out, int out_size, void* d_ws, size_t ws_size,
                              hipStream_t stream) {
  const float* pts   = (const float*)d_in[0];
  const float* ge_w1 = (const float*)d_in[1];
  const float* ge_b1 = (const float*)d_in[2];
  const float* ge_w2 = (const float*)d_in[3];
  const float* ge_b2 = (const float*)d_in[4];
  const float* gd_w1 = (const float*)d_in[5];
  const float* gd_b1 = (const float*)d_in[6];
  const float* gd_w2 = (const float*)d_in[7];
  const float* gd_b2 = (const float*)d_in[8];
  const float* se_w1 = (const float*)d_in[9];
  const float* se_b1 = (const float*)d_in[10];
  const float* sd_w1 = (const float*)d_in[11];
  const float* sd_b1 = (const float*)d_in[12];
  const float* sd_w2 = (const float*)d_in[13];
  const float* sd_b2 = (const float*)d_in[14];
  float* out = (float*)d_out;

  float* ws    = (float*)d_ws;
  float* h1    = ws;                    // 8*256*128 = 262144
  float* codeG = h1 + 262144;           // 2048
  float* recg  = codeG + 2048;          // 6144
  float* ptsg  = recg + 6144;           // 6144
  float* ptsc  = ptsg + 6144;           // 393216
  float* distg = ptsc + 393216;         // 262144

  k_fps<<<NB, 1024, 0, stream>>>(pts, ptsg, distg);
  k_enc1<<<(NB * NG * 128) / 256, 256, 0, stream>>>(ptsg, ge_w1, ge_b1, h1);
  k_code<<<NB, 256, 0, stream>>>(h1, ge_w2, ge_b2, codeG);
  k_dec<<<NB * NG, 256, 0, stream>>>(codeG, gd_w1, gd_b1, gd_w2, gd_b2, recg);
  k_knn_bf<<<NB * NG, 1024, 0, stream>>>(pts, recg, ptsc);
  k_patch<<<NB * NG, 64, 0, stream>>>(ptsc, se_w1, se_b1, sd_w1, sd_b1, sd_w2, sd_b2, out);
}

// Round 11
// 5883.123 us; speedup vs baseline: 1.6898x; 1.6898x over previous
//
#include <hip/hip_runtime.h>

#define NPTS 32768
#define NB 8
#define NG 256

// ---------------- K1: FPS (numpy f32 elementwise, noFMA) ----------------
// Bit-pinned distance math. Selection = lexicographic (max d, min idx) —
// associative, so the parallel reduce tree is bit-identical to serial.
__global__ __launch_bounds__(1024) void k_fps(const float* __restrict__ pts,
                                              float* __restrict__ ptsg,
                                              float* __restrict__ distg) {
  const int b = blockIdx.x;
  const int t = threadIdx.x;
  const float* __restrict__ P = pts + (size_t)b * NPTS * 3;
  float* __restrict__ D = distg + (size_t)b * NPTS;
  float cx[32], cy[32], cz[32];
#pragma unroll
  for (int i = 0; i < 32; ++i) {
    int p = i * 1024 + t;
    cx[i] = P[p * 3 + 0];
    cy[i] = P[p * 3 + 1];
    cz[i] = P[p * 3 + 2];
  }
  __shared__ float rv[16];
  __shared__ int ri[16];
  __shared__ int scur;
  int cur = 0;
  for (int it = 0; it < NG; ++it) {
    float sx = P[cur * 3 + 0], sy = P[cur * 3 + 1], sz = P[cur * 3 + 2];
    if (t == 0) {
      float* G = ptsg + ((size_t)b * NG + it) * 3;
      G[0] = sx; G[1] = sy; G[2] = sz;
    }
    float bv = -1.0f;
    int bi = 0x7fffffff;
#pragma unroll
    for (int i = 0; i < 32; ++i) {
      int p = i * 1024 + t;
      float dx = __fsub_rn(cx[i], sx), dy = __fsub_rn(cy[i], sy), dz = __fsub_rn(cz[i], sz);
      float d = __fadd_rn(__fadd_rn(__fmul_rn(dx, dx), __fmul_rn(dy, dy)),
                          __fmul_rn(dz, dz));
      float nd = d;
      if (it > 0) nd = fminf(D[p], d);
      D[p] = nd;
      if (nd > bv || (nd == bv && p < bi)) { bv = nd; bi = p; }
    }
    for (int off = 32; off > 0; off >>= 1) {
      float ov = __shfl_down(bv, off);
      int oi = __shfl_down(bi, off);
      if (ov > bv || (ov == bv && oi < bi)) { bv = ov; bi = oi; }
    }
    int wid = t >> 6, lane = t & 63;
    if (lane == 0) { rv[wid] = bv; ri[wid] = bi; }
    __syncthreads();
    if (t < 64) {
      float v = (t < 16) ? rv[t] : -2.0f;
      int ix = (t < 16) ? ri[t] : 0x7fffffff;
      for (int off = 8; off > 0; off >>= 1) {
        float ov = __shfl_down(v, off);
        int oi = __shfl_down(ix, off);
        if (ov > v || (ov == v && oi < ix)) { v = ov; ix = oi; }
      }
      if (t == 0) scur = ix;
    }
    __syncthreads();
    cur = scur;
  }
}

// ------ K2: G2SD encoder layer 1 — f32 BLAS-style (seq FMA over K=3) ------
__global__ __launch_bounds__(256) void k_enc1(const float* __restrict__ ptsg,
                                              const float* __restrict__ w1,
                                              const float* __restrict__ b1,
                                              float* __restrict__ h1) {
  int gid = blockIdx.x * 256 + threadIdx.x;
  int f = gid & 127;
  int p = gid >> 7;
  const float* x = ptsg + (size_t)p * 3;
  float acc = __fmul_rn(x[0], w1[0 * 128 + f]);
  acc = fmaf(x[1], w1[1 * 128 + f], acc);
  acc = fmaf(x[2], w1[2 * 128 + f], acc);
  h1[gid] = fmaxf(__fadd_rn(acc, b1[f]), 0.0f);
}

// --- K3: G2SD enc layer 2 + maxpool — f32 seq-FMA over K=128, relu, max ---
__global__ __launch_bounds__(256) void k_code(const float* __restrict__ h1,
                                              const float* __restrict__ w2,
                                              const float* __restrict__ b2,
                                              float* __restrict__ codeG) {
  int b = blockIdx.x;
  int j = threadIdx.x;  // feature 0..255
  float m = -__builtin_inff();
  for (int p = 0; p < 256; ++p) {
    const float* hrow = h1 + ((size_t)b * 256 + p) * 128;
    float acc = __fmul_rn(hrow[0], w2[0 * 256 + j]);
    for (int f = 1; f < 128; ++f)
      acc = fmaf(hrow[f], w2[f * 256 + j], acc);
    float v = fmaxf(__fadd_rn(acc, b2[j]), 0.0f);
    m = fmaxf(m, v);
  }
  codeG[b * 256 + j] = m;
}

// ---- K4: G2SD decoder — f32 seq-FMA (K=258 then K=256), BLAS order -------
__global__ __launch_bounds__(256) void k_dec(const float* __restrict__ codeG,
                                             const float* __restrict__ w1,
                                             const float* __restrict__ b1,
                                             const float* __restrict__ w2,
                                             const float* __restrict__ b2,
                                             float* __restrict__ recg) {
  int blk = blockIdx.x;
  int b = blk >> 8, g = blk & 255;
  int f = threadIdx.x;
  float gx = (float)((((double)(g & 15)) + 0.5) / 16.0);
  float gy = (float)((((double)(g >> 4)) + 0.5) / 16.0);
  const float* code = codeG + b * 256;
  float acc = __fmul_rn(gx, w1[0 * 256 + f]);
  acc = fmaf(gy, w1[1 * 256 + f], acc);
  for (int c = 0; c < 256; ++c)
    acc = fmaf(code[c], w1[(2 + c) * 256 + f], acc);
  float a = fmaxf(__fadd_rn(acc, b1[f]), 0.0f);
  __shared__ float hs[256];
  hs[f] = a;
  __syncthreads();
  if (f < 3) {
    float acc2 = __fmul_rn(hs[0], w2[0 * 3 + f]);
    for (int k = 1; k < 256; ++k)
      acc2 = fmaf(hs[k], w2[k * 3 + f], acc2);
    recg[blk * 3 + f] = __fadd_rn(acc2, b2[f]);
  }
}

// -------- K5: exact stable KNN-64 via radix-select (bit-identical to bf) ---
// Keys: np-f32 _sqdist (ra/rb noFMA seq, ab einsum FMA chain), monotone u32.
// Keys held in 32 VGPRs/thread; 3 histogram passes (11/11/10 bits) with
// wave-0 shfl scan; collect + stable (key,idx) rank-sorted output.
__global__ __launch_bounds__(1024) void k_knn(const float* __restrict__ pts,
                                              const float* __restrict__ recg,
                                              float* __restrict__ ptsc) {
  int bg = blockIdx.x;
  int b = bg >> 8;
  int t = threadIdx.x;
  const float* __restrict__ P = pts + (size_t)b * NPTS * 3;
  float qx = recg[bg * 3 + 0];
  float qy = recg[bg * 3 + 1];
  float qz = recg[bg * 3 + 2];
  float ra = __fadd_rn(__fadd_rn(__fmul_rn(qx, qx), __fmul_rn(qy, qy)),
                       __fmul_rn(qz, qz));
  unsigned kk[32];
#pragma unroll
  for (int i = 0; i < 32; ++i) {
    int p = i * 1024 + t;
    float px = P[p * 3], py = P[p * 3 + 1], pz = P[p * 3 + 2];
    float rb = __fadd_rn(__fadd_rn(__fmul_rn(px, px), __fmul_rn(py, py)),
                         __fmul_rn(pz, pz));
    float ab = fmaf(qz, pz, fmaf(qy, py, __fmul_rn(qx, px)));  // einsum FMA chain
    float d = __fsub_rn(__fadd_rn(ra, rb), __fmul_rn(2.0f, ab));
    unsigned u = __float_as_uint(d);
    u = (u & 0x80000000u) ? ~u : (u | 0x80000000u);  // monotone total order
    kk[i] = u;
  }
  __shared__ unsigned hist[2048];
  __shared__ unsigned s_bin, s_cum;
  __shared__ unsigned s_cntlt, s_cnteq;
  __shared__ unsigned candU[64];
  __shared__ int candI[64];
  __shared__ int eqI_[192];

  unsigned prefix = 0, pmask = 0;
  int rank = 64;
#pragma unroll
  for (int pass = 0; pass < 3; ++pass) {
    const int shift = (pass == 0) ? 21 : (pass == 1) ? 10 : 0;
    const unsigned bm = (pass == 2) ? 1023u : 2047u;
    hist[t] = 0u;
    hist[t + 1024] = 0u;
    __syncthreads();
#pragma unroll
    for (int i = 0; i < 32; ++i) {
      unsigned u = kk[i];
      if ((u & pmask) == prefix) atomicAdd(&hist[(u >> shift) & bm], 1u);
    }
    __syncthreads();
    if (t < 64) {  // wave-0 scan over 2048 bins (32 per lane)
      int base = t * 32;
      unsigned ls = 0;
      for (int k2 = 0; k2 < 32; ++k2) ls += hist[base + k2];
      unsigned incl = ls;
      for (int off = 1; off < 64; off <<= 1) {
        unsigned v = __shfl_up(incl, off);
        if (t >= off) incl += v;
      }
      unsigned excl = incl - ls;
      if ((int)excl < rank && rank <= (int)incl) {
        unsigned c = excl;
        int binf = base;
        for (int k2 = 0; k2 < 32; ++k2) {
          unsigned h = hist[base + k2];
          if ((int)(c + h) >= rank) { binf = base + k2; break; }
          c += h;
        }
        s_bin = (unsigned)binf;
        s_cum = c;
      }
    }
    __syncthreads();
    rank -= (int)s_cum;
    prefix |= (s_bin & bm) << shift;
    pmask |= bm << shift;
  }
  unsigned usel = prefix;
  if (t == 0) { s_cntlt = 0; s_cnteq = 0; }
  __syncthreads();
#pragma unroll
  for (int i = 0; i < 32; ++i) {
    unsigned u = kk[i];
    int p = i * 1024 + t;
    if (u < usel) {
      unsigned pos = atomicAdd(&s_cntlt, 1u);  // total < 64 by construction
      candU[pos] = u; candI[pos] = p;
    } else if (u == usel) {
      unsigned pos = atomicAdd(&s_cnteq, 1u);
      if (pos < 192u) eqI_[pos] = p;
    }
  }
  __syncthreads();
  if (t == 0) {
    int cl = (int)s_cntlt;
    int ne = (int)s_cnteq; if (ne > 192) ne = 192;
    int need = 64 - cl;
    for (int n = 0; n < need; ++n) {  // stable ties: lowest index first
      int bmin = 0x7fffffff, bk2 = -1;
      for (int k2 = 0; k2 < ne; ++k2)
        if (eqI_[k2] < bmin) { bmin = eqI_[k2]; bk2 = k2; }
      candU[cl + n] = usel; candI[cl + n] = bmin;
      if (bk2 >= 0) eqI_[bk2] = 0x7fffffff;
    }
  }
  __syncthreads();
  if (t < 64) {  // stable (key, idx) rank-sort — canonical top_k order
    unsigned mu = candU[t];
    int mi = candI[t];
    int r = 0;
    for (int k2 = 0; k2 < 64; ++k2) {
      unsigned ou = candU[k2]; int oi = candI[k2];
      if (ou < mu || (ou == mu && oi < mi)) ++r;
    }
    float* o = ptsc + ((size_t)bg * 64 + r) * 3;
    o[0] = P[mi * 3]; o[1] = P[mi * 3 + 1]; o[2] = P[mi * 3 + 2];
  }
}

// ---- K6: patch normalize + S2PF + rescale + resample — all f32 BLAS-style --
__device__ inline float wmaxf(float v) {
  for (int off = 1; off < 64; off <<= 1) v = fmaxf(v, __shfl_xor(v, off));
  return v;
}
__device__ inline float wminf(float v) {
  for (int off = 1; off < 64; off <<= 1) v = fminf(v, __shfl_xor(v, off));
  return v;
}

__global__ __launch_bounds__(64) void k_patch(const float* __restrict__ ptsc,
                                              const float* __restrict__ se_w1,
                                              const float* __restrict__ se_b1,
                                              const float* __restrict__ sd_w1,
                                              const float* __restrict__ sd_b1,
                                              const float* __restrict__ sd_w2,
                                              const float* __restrict__ sd_b2,
                                              float* __restrict__ out) {
  int bg = blockIdx.x;
  int b = bg >> 8, g = bg & 255;
  int j = threadIdx.x;
  __shared__ float pc[64][3];
  __shared__ float xn[64][3];
  __shared__ float code[128];
  __shared__ float cmean[3];
  __shared__ float earr[64][2];
  const float* src = ptsc + ((size_t)bg * 64 + j) * 3;
  float p0 = src[0], p1 = src[1], p2 = src[2];
  pc[j][0] = p0; pc[j][1] = p1; pc[j][2] = p2;
  __syncthreads();
  // np.mean over STRIDED axis: plain SEQUENTIAL accumulation k=0..63
  if (j < 3) {
    float sum = pc[0][j];
    for (int k = 1; k < 64; ++k) sum = __fadd_rn(sum, pc[k][j]);
    cmean[j] = __fdiv_rn(sum, 64.0f);
  }
  __syncthreads();
  float x0 = __fsub_rn(p0, cmean[0]);
  float x1 = __fsub_rn(p1, cmean[1]);
  float x2 = __fsub_rn(p2, cmean[2]);
  float nr = sqrtf(__fadd_rn(__fadd_rn(__fmul_rn(x0, x0), __fmul_rn(x1, x1)),
                             __fmul_rn(x2, x2)));
  float s = wmaxf(nr);
  float den = __fadd_rn(s, 1e-8f);
  x0 = __fdiv_rn(x0, den);
  x1 = __fdiv_rn(x1, den);
  x2 = __fdiv_rn(x2, den);
  xn[j][0] = x0; xn[j][1] = x1; xn[j][2] = x2;
  __syncthreads();
  // per-point encoder (K=3, seq FMA) + relu + maxpool -> code[128]
  for (int ff = 0; ff < 2; ++ff) {
    int f = j + ff * 64;
    float w0 = se_w1[0 * 128 + f];
    float w1v = se_w1[1 * 128 + f];
    float w2v = se_w1[2 * 128 + f];
    float bb = se_b1[f];
    float m = -__builtin_inff();
    for (int p = 0; p < 64; ++p) {
      float acc = __fmul_rn(xn[p][0], w0);
      acc = fmaf(xn[p][1], w1v, acc);
      acc = fmaf(xn[p][2], w2v, acc);
      float v = fmaxf(__fadd_rn(acc, bb), 0.0f);
      m = fmaxf(m, v);
    }
    code[f] = m;
  }
  __syncthreads();
  // sd layer1 (K=131: x then code, seq FMA) -> relu -> layer2 (K=128 seq FMA)
  float pe0 = 0.0f, pe1 = 0.0f;
  for (int f = 0; f < 128; ++f) {
    float acc = __fmul_rn(x0, sd_w1[0 * 128 + f]);
    acc = fmaf(x1, sd_w1[1 * 128 + f], acc);
    acc = fmaf(x2, sd_w1[2 * 128 + f], acc);
    for (int c = 0; c < 128; ++c)
      acc = fmaf(code[c], sd_w1[(3 + c) * 128 + f], acc);
    float h = fmaxf(__fadd_rn(acc, sd_b1[f]), 0.0f);
    if (f == 0) {
      pe0 = __fmul_rn(h, sd_w2[0 * 2 + 0]);
      pe1 = __fmul_rn(h, sd_w2[0 * 2 + 1]);
    } else {
      pe0 = fmaf(h, sd_w2[f * 2 + 0], pe0);
      pe1 = fmaf(h, sd_w2[f * 2 + 1], pe1);
    }
  }
  pe0 = __fadd_rn(pe0, sd_b2[0]);
  pe1 = __fadd_rn(pe1, sd_b2[1]);
  // rescale_pe, numpy elementwise op order, f32
  float mn0 = wminf(pe0), mx0 = wmaxf(pe0);
  float mn1 = wminf(pe1), mx1 = wmaxf(pe1);
  const float SPAN = (float)0.999998;
  float e0 = __fadd_rn(__fmul_rn(__fdiv_rn(__fsub_rn(pe0, mn0),
                                           __fadd_rn(__fsub_rn(mx0, mn0), 1e-8f)),
                                 SPAN), 1e-6f);
  float e1 = __fadd_rn(__fmul_rn(__fdiv_rn(__fsub_rn(pe1, mn1),
                                           __fadd_rn(__fsub_rn(mx1, mn1), 1e-8f)),
                                 SPAN), 1e-6f);
  earr[j][0] = e0;
  earr[j][1] = e1;
  __syncthreads();
  // serial per-cell argmin (np.argmin first-occurrence, f32 noFMA)
  if (j < 16) {
    float gxf = (float)((((double)(j & 3)) + 0.5) * 0.25);
    float gyf = (float)((((double)(j >> 2)) + 0.5) * 0.25);
    float best = __builtin_inff();
    int bi = 0;
    for (int sslot = 0; sslot < 64; ++sslot) {
      float dx = __fsub_rn(gxf, earr[sslot][0]);
      float dy = __fsub_rn(gyf, earr[sslot][1]);
      float d2 = __fadd_rn(__fmul_rn(dx, dx), __fmul_rn(dy, dy));
      if (d2 < best) { best = d2; bi = sslot; }
    }
    int rr = (g >> 4) * 4 + (j >> 2);
    int cc = (g & 15) * 4 + (j & 3);
    float* o = out + (((size_t)b * 4096) + (size_t)(rr * 64 + cc)) * 3;
    o[0] = pc[bi][0]; o[1] = pc[bi][1]; o[2] = pc[bi][2];
  }
}

extern "C" void kernel_launch(void* const* d_in, const int* in_sizes, int n_in,
                              void* d_out, int out_size, void* d_ws, size_t ws_size,
                              hipStream_t stream) {
  const float* pts   = (const float*)d_in[0];
  const float* ge_w1 = (const float*)d_in[1];
  const float* ge_b1 = (const float*)d_in[2];
  const float* ge_w2 = (const float*)d_in[3];
  const float* ge_b2 = (const float*)d_in[4];
  const float* gd_w1 = (const float*)d_in[5];
  const float* gd_b1 = (const float*)d_in[6];
  const float* gd_w2 = (const float*)d_in[7];
  const float* gd_b2 = (const float*)d_in[8];
  const float* se_w1 = (const float*)d_in[9];
  const float* se_b1 = (const float*)d_in[10];
  const float* sd_w1 = (const float*)d_in[11];
  const float* sd_b1 = (const float*)d_in[12];
  const float* sd_w2 = (const float*)d_in[13];
  const float* sd_b2 = (const float*)d_in[14];
  float* out = (float*)d_out;

  float* ws    = (float*)d_ws;
  float* h1    = ws;                    // 8*256*128 = 262144
  float* codeG = h1 + 262144;           // 2048
  float* recg  = codeG + 2048;          // 6144
  float* ptsg  = recg + 6144;           // 6144
  float* ptsc  = ptsg + 6144;           // 393216
  float* distg = ptsc + 393216;         // 262144

  k_fps<<<NB, 1024, 0, stream>>>(pts, ptsg, distg);
  k_enc1<<<(NB * NG * 128) / 256, 256, 0, stream>>>(ptsg, ge_w1, ge_b1, h1);
  k_code<<<NB, 256, 0, stream>>>(h1, ge_w2, ge_b2, codeG);
  k_dec<<<NB * NG, 256, 0, stream>>>(codeG, gd_w1, gd_b1, gd_w2, gd_b2, recg);
  k_knn<<<NB * NG, 1024, 0, stream>>>(pts, recg, ptsc);
  k_patch<<<NB * NG, 64, 0, stream>>>(ptsc, se_w1, se_b1, sd_w1, sd_b1, sd_w2, sd_b2, out);
}

// Round 12
// 3224.420 us; speedup vs baseline: 3.0831x; 1.8246x over previous
//
#include <hip/hip_runtime.h>

#define NPTS 32768
#define NB 8
#define NG 256

// ---------------- K1: FPS (numpy f32 elementwise, noFMA) ----------------
// Bit-pinned distance math. D (running min) lives in LDS (128 KiB);
// coords cached in 96 VGPRs (launch_bounds 1024,4 -> 128 VGPR budget).
__global__ __launch_bounds__(1024, 4) void k_fps(const float* __restrict__ pts,
                                                 float* __restrict__ ptsg) {
  const int b = blockIdx.x;
  const int t = threadIdx.x;
  const float* __restrict__ P = pts + (size_t)b * NPTS * 3;
  __shared__ float Dl[NPTS];  // 128 KiB
  float cx[32], cy[32], cz[32];
#pragma unroll
  for (int i = 0; i < 32; ++i) {
    int p = i * 1024 + t;
    cx[i] = P[p * 3 + 0];
    cy[i] = P[p * 3 + 1];
    cz[i] = P[p * 3 + 2];
  }
  __shared__ float rv[16];
  __shared__ int ri[16];
  __shared__ int scur;
  int cur = 0;
  for (int it = 0; it < NG; ++it) {
    float sx = P[cur * 3 + 0], sy = P[cur * 3 + 1], sz = P[cur * 3 + 2];
    if (t == 0) {
      float* G = ptsg + ((size_t)b * NG + it) * 3;
      G[0] = sx; G[1] = sy; G[2] = sz;
    }
    float bv = -1.0f;
    int bi = 0x7fffffff;
#pragma unroll
    for (int i = 0; i < 32; ++i) {
      int p = i * 1024 + t;
      float dx = __fsub_rn(cx[i], sx), dy = __fsub_rn(cy[i], sy), dz = __fsub_rn(cz[i], sz);
      float d = __fadd_rn(__fadd_rn(__fmul_rn(dx, dx), __fmul_rn(dy, dy)),
                          __fmul_rn(dz, dz));
      float nd = d;
      if (it > 0) nd = fminf(Dl[p], d);
      Dl[p] = nd;
      if (nd > bv || (nd == bv && p < bi)) { bv = nd; bi = p; }
    }
    for (int off = 32; off > 0; off >>= 1) {
      float ov = __shfl_down(bv, off);
      int oi = __shfl_down(bi, off);
      if (ov > bv || (ov == bv && oi < bi)) { bv = ov; bi = oi; }
    }
    int wid = t >> 6, lane = t & 63;
    if (lane == 0) { rv[wid] = bv; ri[wid] = bi; }
    __syncthreads();
    if (t < 64) {
      float v = (t < 16) ? rv[t] : -2.0f;
      int ix = (t < 16) ? ri[t] : 0x7fffffff;
      for (int off = 8; off > 0; off >>= 1) {
        float ov = __shfl_down(v, off);
        int oi = __shfl_down(ix, off);
        if (ov > v || (ov == v && oi < ix)) { v = ov; ix = oi; }
      }
      if (t == 0) scur = ix;
    }
    __syncthreads();
    cur = scur;
  }
}

// ------ K2: G2SD encoder layer 1 — f32 BLAS-style (seq FMA over K=3) ------
__global__ __launch_bounds__(256) void k_enc1(const float* __restrict__ ptsg,
                                              const float* __restrict__ w1,
                                              const float* __restrict__ b1,
                                              float* __restrict__ h1) {
  int gid = blockIdx.x * 256 + threadIdx.x;
  int f = gid & 127;
  int p = gid >> 7;
  const float* x = ptsg + (size_t)p * 3;
  float acc = __fmul_rn(x[0], w1[0 * 128 + f]);
  acc = fmaf(x[1], w1[1 * 128 + f], acc);
  acc = fmaf(x[2], w1[2 * 128 + f], acc);
  h1[gid] = fmaxf(__fadd_rn(acc, b1[f]), 0.0f);
}

// --- K3: G2SD enc layer 2 + maxpool — f32 seq-FMA over K=128, relu, max ---
__global__ __launch_bounds__(256) void k_code(const float* __restrict__ h1,
                                              const float* __restrict__ w2,
                                              const float* __restrict__ b2,
                                              float* __restrict__ codeG) {
  int b = blockIdx.x;
  int j = threadIdx.x;  // feature 0..255
  float m = -__builtin_inff();
  for (int p = 0; p < 256; ++p) {
    const float* hrow = h1 + ((size_t)b * 256 + p) * 128;
    float acc = __fmul_rn(hrow[0], w2[0 * 256 + j]);
    for (int f = 1; f < 128; ++f)
      acc = fmaf(hrow[f], w2[f * 256 + j], acc);
    float v = fmaxf(__fadd_rn(acc, b2[j]), 0.0f);
    m = fmaxf(m, v);
  }
  codeG[b * 256 + j] = m;
}

// ---- K4: G2SD decoder — f32 seq-FMA (K=258 then K=256), BLAS order -------
__global__ __launch_bounds__(256) void k_dec(const float* __restrict__ codeG,
                                             const float* __restrict__ w1,
                                             const float* __restrict__ b1,
                                             const float* __restrict__ w2,
                                             const float* __restrict__ b2,
                                             float* __restrict__ recg) {
  int blk = blockIdx.x;
  int b = blk >> 8, g = blk & 255;
  int f = threadIdx.x;
  float gx = (float)((((double)(g & 15)) + 0.5) / 16.0);
  float gy = (float)((((double)(g >> 4)) + 0.5) / 16.0);
  const float* code = codeG + b * 256;
  float acc = __fmul_rn(gx, w1[0 * 256 + f]);
  acc = fmaf(gy, w1[1 * 256 + f], acc);
  for (int c = 0; c < 256; ++c)
    acc = fmaf(code[c], w1[(2 + c) * 256 + f], acc);
  float a = fmaxf(__fadd_rn(acc, b1[f]), 0.0f);
  __shared__ float hs[256];
  hs[f] = a;
  __syncthreads();
  if (f < 3) {
    float acc2 = __fmul_rn(hs[0], w2[0 * 3 + f]);
    for (int k = 1; k < 256; ++k)
      acc2 = fmaf(hs[k], w2[k * 3 + f], acc2);
    recg[blk * 3 + f] = __fadd_rn(acc2, b2[f]);
  }
}

// -------- K5: exact stable KNN-64 via radix-select (bit-identical to bf) ---
__global__ __launch_bounds__(1024) void k_knn(const float* __restrict__ pts,
                                              const float* __restrict__ recg,
                                              float* __restrict__ ptsc) {
  int bg = blockIdx.x;
  int b = bg >> 8;
  int t = threadIdx.x;
  const float* __restrict__ P = pts + (size_t)b * NPTS * 3;
  float qx = recg[bg * 3 + 0];
  float qy = recg[bg * 3 + 1];
  float qz = recg[bg * 3 + 2];
  float ra = __fadd_rn(__fadd_rn(__fmul_rn(qx, qx), __fmul_rn(qy, qy)),
                       __fmul_rn(qz, qz));
  unsigned kk[32];
#pragma unroll
  for (int i = 0; i < 32; ++i) {
    int p = i * 1024 + t;
    float px = P[p * 3], py = P[p * 3 + 1], pz = P[p * 3 + 2];
    float rb = __fadd_rn(__fadd_rn(__fmul_rn(px, px), __fmul_rn(py, py)),
                         __fmul_rn(pz, pz));
    float ab = fmaf(qz, pz, fmaf(qy, py, __fmul_rn(qx, px)));  // einsum FMA chain
    float d = __fsub_rn(__fadd_rn(ra, rb), __fmul_rn(2.0f, ab));
    unsigned u = __float_as_uint(d);
    u = (u & 0x80000000u) ? ~u : (u | 0x80000000u);  // monotone total order
    kk[i] = u;
  }
  __shared__ unsigned hist[2048];
  __shared__ unsigned s_bin, s_cum;
  __shared__ unsigned s_cntlt, s_cnteq;
  __shared__ unsigned candU[64];
  __shared__ int candI[64];
  __shared__ int eqI_[192];

  unsigned prefix = 0, pmask = 0;
  int rank = 64;
#pragma unroll
  for (int pass = 0; pass < 3; ++pass) {
    const int shift = (pass == 0) ? 21 : (pass == 1) ? 10 : 0;
    const unsigned bm = (pass == 2) ? 1023u : 2047u;
    hist[t] = 0u;
    hist[t + 1024] = 0u;
    __syncthreads();
#pragma unroll
    for (int i = 0; i < 32; ++i) {
      unsigned u = kk[i];
      if ((u & pmask) == prefix) atomicAdd(&hist[(u >> shift) & bm], 1u);
    }
    __syncthreads();
    if (t < 64) {  // wave-0 scan over 2048 bins (32 per lane)
      int base = t * 32;
      unsigned ls = 0;
      for (int k2 = 0; k2 < 32; ++k2) ls += hist[base + k2];
      unsigned incl = ls;
      for (int off = 1; off < 64; off <<= 1) {
        unsigned v = __shfl_up(incl, off);
        if (t >= off) incl += v;
      }
      unsigned excl = incl - ls;
      if ((int)excl < rank && rank <= (int)incl) {
        unsigned c = excl;
        int binf = base;
        for (int k2 = 0; k2 < 32; ++k2) {
          unsigned h = hist[base + k2];
          if ((int)(c + h) >= rank) { binf = base + k2; break; }
          c += h;
        }
        s_bin = (unsigned)binf;
        s_cum = c;
      }
    }
    __syncthreads();
    rank -= (int)s_cum;
    prefix |= (s_bin & bm) << shift;
    pmask |= bm << shift;
  }
  unsigned usel = prefix;
  if (t == 0) { s_cntlt = 0; s_cnteq = 0; }
  __syncthreads();
#pragma unroll
  for (int i = 0; i < 32; ++i) {
    unsigned u = kk[i];
    int p = i * 1024 + t;
    if (u < usel) {
      unsigned pos = atomicAdd(&s_cntlt, 1u);  // total < 64 by construction
      candU[pos] = u; candI[pos] = p;
    } else if (u == usel) {
      unsigned pos = atomicAdd(&s_cnteq, 1u);
      if (pos < 192u) eqI_[pos] = p;
    }
  }
  __syncthreads();
  if (t == 0) {
    int cl = (int)s_cntlt;
    int ne = (int)s_cnteq; if (ne > 192) ne = 192;
    int need = 64 - cl;
    for (int n = 0; n < need; ++n) {  // stable ties: lowest index first
      int bmin = 0x7fffffff, bk2 = -1;
      for (int k2 = 0; k2 < ne; ++k2)
        if (eqI_[k2] < bmin) { bmin = eqI_[k2]; bk2 = k2; }
      candU[cl + n] = usel; candI[cl + n] = bmin;
      if (bk2 >= 0) eqI_[bk2] = 0x7fffffff;
    }
  }
  __syncthreads();
  if (t < 64) {  // stable (key, idx) rank-sort — canonical top_k order
    unsigned mu = candU[t];
    int mi = candI[t];
    int r = 0;
    for (int k2 = 0; k2 < 64; ++k2) {
      unsigned ou = candU[k2]; int oi = candI[k2];
      if (ou < mu || (ou == mu && oi < mi)) ++r;
    }
    float* o = ptsc + ((size_t)bg * 64 + r) * 3;
    o[0] = P[mi * 3]; o[1] = P[mi * 3 + 1]; o[2] = P[mi * 3 + 2];
  }
}

// ---- K6: patch normalize + S2PF + rescale + resample — all f32 BLAS-style --
__device__ inline float wmaxf(float v) {
  for (int off = 1; off < 64; off <<= 1) v = fmaxf(v, __shfl_xor(v, off));
  return v;
}
__device__ inline float wminf(float v) {
  for (int off = 1; off < 64; off <<= 1) v = fminf(v, __shfl_xor(v, off));
  return v;
}

__global__ __launch_bounds__(64) void k_patch(const float* __restrict__ ptsc,
                                              const float* __restrict__ se_w1,
                                              const float* __restrict__ se_b1,
                                              const float* __restrict__ sd_w1,
                                              const float* __restrict__ sd_b1,
                                              const float* __restrict__ sd_w2,
                                              const float* __restrict__ sd_b2,
                                              float* __restrict__ out) {
  int bg = blockIdx.x;
  int b = bg >> 8, g = bg & 255;
  int j = threadIdx.x;
  __shared__ float pc[64][3];
  __shared__ float xn[64][3];
  __shared__ float code[128];
  __shared__ float cmean[3];
  __shared__ float earr[64][2];
  const float* src = ptsc + ((size_t)bg * 64 + j) * 3;
  float p0 = src[0], p1 = src[1], p2 = src[2];
  pc[j][0] = p0; pc[j][1] = p1; pc[j][2] = p2;
  __syncthreads();
  // np.mean over STRIDED axis: plain SEQUENTIAL accumulation k=0..63
  if (j < 3) {
    float sum = pc[0][j];
    for (int k = 1; k < 64; ++k) sum = __fadd_rn(sum, pc[k][j]);
    cmean[j] = __fdiv_rn(sum, 64.0f);
  }
  __syncthreads();
  float x0 = __fsub_rn(p0, cmean[0]);
  float x1 = __fsub_rn(p1, cmean[1]);
  float x2 = __fsub_rn(p2, cmean[2]);
  float nr = sqrtf(__fadd_rn(__fadd_rn(__fmul_rn(x0, x0), __fmul_rn(x1, x1)),
                             __fmul_rn(x2, x2)));
  float s = wmaxf(nr);
  float den = __fadd_rn(s, 1e-8f);
  x0 = __fdiv_rn(x0, den);
  x1 = __fdiv_rn(x1, den);
  x2 = __fdiv_rn(x2, den);
  xn[j][0] = x0; xn[j][1] = x1; xn[j][2] = x2;
  __syncthreads();
  // per-point encoder (K=3, seq FMA) + relu + maxpool -> code[128]
  for (int ff = 0; ff < 2; ++ff) {
    int f = j + ff * 64;
    float w0 = se_w1[0 * 128 + f];
    float w1v = se_w1[1 * 128 + f];
    float w2v = se_w1[2 * 128 + f];
    float bb = se_b1[f];
    float m = -__builtin_inff();
    for (int p = 0; p < 64; ++p) {
      float acc = __fmul_rn(xn[p][0], w0);
      acc = fmaf(xn[p][1], w1v, acc);
      acc = fmaf(xn[p][2], w2v, acc);
      float v = fmaxf(__fadd_rn(acc, bb), 0.0f);
      m = fmaxf(m, v);
    }
    code[f] = m;
  }
  __syncthreads();
  // sd layer1 (K=131: x then code, seq FMA) -> relu -> layer2 (K=128 seq FMA)
  float pe0 = 0.0f, pe1 = 0.0f;
  for (int f = 0; f < 128; ++f) {
    float acc = __fmul_rn(x0, sd_w1[0 * 128 + f]);
    acc = fmaf(x1, sd_w1[1 * 128 + f], acc);
    acc = fmaf(x2, sd_w1[2 * 128 + f], acc);
    for (int c = 0; c < 128; ++c)
      acc = fmaf(code[c], sd_w1[(3 + c) * 128 + f], acc);
    float h = fmaxf(__fadd_rn(acc, sd_b1[f]), 0.0f);
    if (f == 0) {
      pe0 = __fmul_rn(h, sd_w2[0 * 2 + 0]);
      pe1 = __fmul_rn(h, sd_w2[0 * 2 + 1]);
    } else {
      pe0 = fmaf(h, sd_w2[f * 2 + 0], pe0);
      pe1 = fmaf(h, sd_w2[f * 2 + 1], pe1);
    }
  }
  pe0 = __fadd_rn(pe0, sd_b2[0]);
  pe1 = __fadd_rn(pe1, sd_b2[1]);
  // rescale_pe, numpy elementwise op order, f32
  float mn0 = wminf(pe0), mx0 = wmaxf(pe0);
  float mn1 = wminf(pe1), mx1 = wmaxf(pe1);
  const float SPAN = (float)0.999998;
  float e0 = __fadd_rn(__fmul_rn(__fdiv_rn(__fsub_rn(pe0, mn0),
                                           __fadd_rn(__fsub_rn(mx0, mn0), 1e-8f)),
                                 SPAN), 1e-6f);
  float e1 = __fadd_rn(__fmul_rn(__fdiv_rn(__fsub_rn(pe1, mn1),
                                           __fadd_rn(__fsub_rn(mx1, mn1), 1e-8f)),
                                 SPAN), 1e-6f);
  earr[j][0] = e0;
  earr[j][1] = e1;
  __syncthreads();
  // serial per-cell argmin (np.argmin first-occurrence, f32 noFMA)
  if (j < 16) {
    float gxf = (float)((((double)(j & 3)) + 0.5) * 0.25);
    float gyf = (float)((((double)(j >> 2)) + 0.5) * 0.25);
    float best = __builtin_inff();
    int bi = 0;
    for (int sslot = 0; sslot < 64; ++sslot) {
      float dx = __fsub_rn(gxf, earr[sslot][0]);
      float dy = __fsub_rn(gyf, earr[sslot][1]);
      float d2 = __fadd_rn(__fmul_rn(dx, dx), __fmul_rn(dy, dy));
      if (d2 < best) { best = d2; bi = sslot; }
    }
    int rr = (g >> 4) * 4 + (j >> 2);
    int cc = (g & 15) * 4 + (j & 3);
    float* o = out + (((size_t)b * 4096) + (size_t)(rr * 64 + cc)) * 3;
    o[0] = pc[bi][0]; o[1] = pc[bi][1]; o[2] = pc[bi][2];
  }
}

extern "C" void kernel_launch(void* const* d_in, const int* in_sizes, int n_in,
                              void* d_out, int out_size, void* d_ws, size_t ws_size,
                              hipStream_t stream) {
  const float* pts   = (const float*)d_in[0];
  const float* ge_w1 = (const float*)d_in[1];
  const float* ge_b1 = (const float*)d_in[2];
  const float* ge_w2 = (const float*)d_in[3];
  const float* ge_b2 = (const float*)d_in[4];
  const float* gd_w1 = (const float*)d_in[5];
  const float* gd_b1 = (const float*)d_in[6];
  const float* gd_w2 = (const float*)d_in[7];
  const float* gd_b2 = (const float*)d_in[8];
  const float* se_w1 = (const float*)d_in[9];
  const float* se_b1 = (const float*)d_in[10];
  const float* sd_w1 = (const float*)d_in[11];
  const float* sd_b1 = (const float*)d_in[12];
  const float* sd_w2 = (const float*)d_in[13];
  const float* sd_b2 = (const float*)d_in[14];
  float* out = (float*)d_out;

  float* ws    = (float*)d_ws;
  float* h1    = ws;                    // 8*256*128 = 262144
  float* codeG = h1 + 262144;           // 2048
  float* recg  = codeG + 2048;          // 6144
  float* ptsg  = recg + 6144;           // 6144
  float* ptsc  = ptsg + 6144;           // 393216

  k_fps<<<NB, 1024, 0, stream>>>(pts, ptsg);
  k_enc1<<<(NB * NG * 128) / 256, 256, 0, stream>>>(ptsg, ge_w1, ge_b1, h1);
  k_code<<<NB, 256, 0, stream>>>(h1, ge_w2, ge_b2, codeG);
  k_dec<<<NB * NG, 256, 0, stream>>>(codeG, gd_w1, gd_b1, gd_w2, gd_b2, recg);
  k_knn<<<NB * NG, 1024, 0, stream>>>(pts, recg, ptsc);
  k_patch<<<NB * NG, 64, 0, stream>>>(ptsc, se_w1, se_b1, sd_w1, sd_b1, sd_w2, sd_b2, out);
}

// Round 13
// 2868.545 us; speedup vs baseline: 3.4656x; 1.1241x over previous
//
#include <hip/hip_runtime.h>

#define NPTS 32768
#define NB 8
#define NG 256
#define REGPTS 12
#define RELPTS 20
#define RELBASE (REGPTS * 1024)   // 12288

// ---------------- K1: FPS (numpy f32 elementwise, noFMA) ----------------
// Bit-pinned distance math. D in LDS (128 KiB, owner-thread-only access).
// 12 pts/thread reg-cached, 20 pts/thread reloaded per iter via float4.
// Single barrier/iter: parity-buffered rv/ri + per-wave redundant reduce
// (lexicographic (max d, min idx) is associative -> bit-identical winner).
__global__ __launch_bounds__(1024, 4) void k_fps(const float* __restrict__ pts,
                                                 float* __restrict__ ptsg) {
  const int b = blockIdx.x;
  const int t = threadIdx.x;
  const float* __restrict__ P = pts + (size_t)b * NPTS * 3;
  const float4* __restrict__ P4 =
      reinterpret_cast<const float4*>(P + (size_t)RELBASE * 3);
  __shared__ float Dl[NPTS];  // 128 KiB
  __shared__ float rv[2][16];
  __shared__ int ri[2][16];
  float cx[REGPTS], cy[REGPTS], cz[REGPTS];
#pragma unroll
  for (int i = 0; i < REGPTS; ++i) {
    int p = i * 1024 + t;
    cx[i] = P[p * 3 + 0];
    cy[i] = P[p * 3 + 1];
    cz[i] = P[p * 3 + 2];
  }
  int cur = 0;
  for (int it = 0; it < NG; ++it) {
    float sx = P[cur * 3 + 0], sy = P[cur * 3 + 1], sz = P[cur * 3 + 2];
    if (t == 0) {
      float* G = ptsg + ((size_t)b * NG + it) * 3;
      G[0] = sx; G[1] = sy; G[2] = sz;
    }
    float bv = -1.0f;
    int bi = 0x7fffffff;
#pragma unroll
    for (int i = 0; i < REGPTS; ++i) {
      int p = i * 1024 + t;
      float dx = __fsub_rn(cx[i], sx), dy = __fsub_rn(cy[i], sy), dz = __fsub_rn(cz[i], sz);
      float d = __fadd_rn(__fadd_rn(__fmul_rn(dx, dx), __fmul_rn(dy, dy)),
                          __fmul_rn(dz, dz));
      float nd = d;
      if (it > 0) nd = fminf(Dl[p], d);
      Dl[p] = nd;
      if (nd > bv || (nd == bv && p < bi)) { bv = nd; bi = p; }
    }
    // reload half: 20 contiguous points per thread, float4 groups of 4 pts
#pragma unroll
    for (int g = 0; g < 5; ++g) {
      float4 q0 = P4[t * 15 + g * 3 + 0];
      float4 q1 = P4[t * 15 + g * 3 + 1];
      float4 q2 = P4[t * 15 + g * 3 + 2];
      float xs[12] = {q0.x, q0.y, q0.z, q0.w, q1.x, q1.y, q1.z, q1.w,
                      q2.x, q2.y, q2.z, q2.w};
#pragma unroll
      for (int j = 0; j < 4; ++j) {
        int p = RELBASE + t * RELPTS + g * 4 + j;
        float dx = __fsub_rn(xs[j * 3 + 0], sx);
        float dy = __fsub_rn(xs[j * 3 + 1], sy);
        float dz = __fsub_rn(xs[j * 3 + 2], sz);
        float d = __fadd_rn(__fadd_rn(__fmul_rn(dx, dx), __fmul_rn(dy, dy)),
                            __fmul_rn(dz, dz));
        float nd = d;
        if (it > 0) nd = fminf(Dl[p], d);
        Dl[p] = nd;
        if (nd > bv || (nd == bv && p < bi)) { bv = nd; bi = p; }
      }
    }
    for (int off = 32; off > 0; off >>= 1) {
      float ov = __shfl_down(bv, off);
      int oi = __shfl_down(bi, off);
      if (ov > bv || (ov == bv && oi < bi)) { bv = ov; bi = oi; }
    }
    int par = it & 1;
    int wid = t >> 6, lane = t & 63;
    if (lane == 0) { rv[par][wid] = bv; ri[par][wid] = bi; }
    __syncthreads();
    // every wave reduces rv/ri independently (no 2nd barrier)
    {
      float v = (lane < 16) ? rv[par][lane] : -2.0f;
      int ix = (lane < 16) ? ri[par][lane] : 0x7fffffff;
      for (int off = 8; off > 0; off >>= 1) {
        float ov = __shfl_down(v, off);
        int oi = __shfl_down(ix, off);
        if (ov > v || (ov == v && oi < ix)) { v = ov; ix = oi; }
      }
      cur = __shfl(ix, 0);
    }
  }
}

// ------ K2: G2SD encoder layer 1 — f32 BLAS-style (seq FMA over K=3) ------
__global__ __launch_bounds__(256) void k_enc1(const float* __restrict__ ptsg,
                                              const float* __restrict__ w1,
                                              const float* __restrict__ b1,
                                              float* __restrict__ h1) {
  int gid = blockIdx.x * 256 + threadIdx.x;
  int f = gid & 127;
  int p = gid >> 7;
  const float* x = ptsg + (size_t)p * 3;
  float acc = __fmul_rn(x[0], w1[0 * 128 + f]);
  acc = fmaf(x[1], w1[1 * 128 + f], acc);
  acc = fmaf(x[2], w1[2 * 128 + f], acc);
  h1[gid] = fmaxf(__fadd_rn(acc, b1[f]), 0.0f);
}

// --- K3: enc layer 2 + maxpool — 4 threads/feature, 64 pts each (max assoc) -
__global__ __launch_bounds__(1024) void k_code(const float* __restrict__ h1,
                                               const float* __restrict__ w2,
                                               const float* __restrict__ b2,
                                               float* __restrict__ codeG) {
  int b = blockIdx.x;
  int t = threadIdx.x;
  int j = t & 255;
  int q = t >> 8;  // 0..3
  __shared__ float part[4][256];
  float m = -__builtin_inff();
  for (int p = q * 64; p < q * 64 + 64; ++p) {
    const float* hrow = h1 + ((size_t)b * 256 + p) * 128;
    float acc = __fmul_rn(hrow[0], w2[0 * 256 + j]);
    for (int f = 1; f < 128; ++f)
      acc = fmaf(hrow[f], w2[f * 256 + j], acc);
    float v = fmaxf(__fadd_rn(acc, b2[j]), 0.0f);
    m = fmaxf(m, v);
  }
  part[q][j] = m;
  __syncthreads();
  if (q == 0)
    codeG[b * 256 + j] =
        fmaxf(fmaxf(part[0][j], part[1][j]), fmaxf(part[2][j], part[3][j]));
}

// ---- K4: G2SD decoder — f32 seq-FMA (K=258 then K=256), BLAS order -------
__global__ __launch_bounds__(256) void k_dec(const float* __restrict__ codeG,
                                             const float* __restrict__ w1,
                                             const float* __restrict__ b1,
                                             const float* __restrict__ w2,
                                             const float* __restrict__ b2,
                                             float* __restrict__ recg) {
  int blk = blockIdx.x;
  int b = blk >> 8, g = blk & 255;
  int f = threadIdx.x;
  float gx = (float)((((double)(g & 15)) + 0.5) / 16.0);
  float gy = (float)((((double)(g >> 4)) + 0.5) / 16.0);
  const float* code = codeG + b * 256;
  float acc = __fmul_rn(gx, w1[0 * 256 + f]);
  acc = fmaf(gy, w1[1 * 256 + f], acc);
  for (int c = 0; c < 256; ++c)
    acc = fmaf(code[c], w1[(2 + c) * 256 + f], acc);
  float a = fmaxf(__fadd_rn(acc, b1[f]), 0.0f);
  __shared__ float hs[256];
  hs[f] = a;
  __syncthreads();
  if (f < 3) {
    float acc2 = __fmul_rn(hs[0], w2[0 * 3 + f]);
    for (int k = 1; k < 256; ++k)
      acc2 = fmaf(hs[k], w2[k * 3 + f], acc2);
    recg[blk * 3 + f] = __fadd_rn(acc2, b2[f]);
  }
}

// -------- K5: exact stable KNN-64, 4x8-bit radix w/ per-wave histograms ----
// Same keys (np _sqdist f32), same selected set/order — counts are exact
// integers, so the 64th-key threshold is identical to the 3-pass version.
__global__ __launch_bounds__(1024) void k_knn(const float* __restrict__ pts,
                                              const float* __restrict__ recg,
                                              float* __restrict__ ptsc) {
  int bg = blockIdx.x;
  int b = bg >> 8;
  int t = threadIdx.x;
  const float* __restrict__ P = pts + (size_t)b * NPTS * 3;
  float qx = recg[bg * 3 + 0];
  float qy = recg[bg * 3 + 1];
  float qz = recg[bg * 3 + 2];
  float ra = __fadd_rn(__fadd_rn(__fmul_rn(qx, qx), __fmul_rn(qy, qy)),
                       __fmul_rn(qz, qz));
  unsigned kk[32];
#pragma unroll
  for (int i = 0; i < 32; ++i) {
    int p = i * 1024 + t;
    float px = P[p * 3], py = P[p * 3 + 1], pz = P[p * 3 + 2];
    float rb = __fadd_rn(__fadd_rn(__fmul_rn(px, px), __fmul_rn(py, py)),
                         __fmul_rn(pz, pz));
    float ab = fmaf(qz, pz, fmaf(qy, py, __fmul_rn(qx, px)));  // einsum FMA chain
    float d = __fsub_rn(__fadd_rn(ra, rb), __fmul_rn(2.0f, ab));
    unsigned u = __float_as_uint(d);
    u = (u & 0x80000000u) ? ~u : (u | 0x80000000u);  // monotone total order
    kk[i] = u;
  }
  __shared__ unsigned whist[16][256];  // per-wave histograms (16 KiB)
  __shared__ unsigned chist[256];
  __shared__ unsigned s_bin, s_cum;
  __shared__ unsigned s_cntlt, s_cnteq;
  __shared__ unsigned candU[64];
  __shared__ int candI[64];
  __shared__ int eqI_[192];
  int wid = t >> 6;

  unsigned prefix = 0, pmask = 0;
  int rank = 64;
#pragma unroll
  for (int pass = 0; pass < 4; ++pass) {
    const int shift = 24 - 8 * pass;
    unsigned* wh = &whist[0][0];
    for (int k2 = t; k2 < 16 * 256; k2 += 1024) wh[k2] = 0u;
    __syncthreads();
#pragma unroll
    for (int i = 0; i < 32; ++i) {
      unsigned u = kk[i];
      if ((u & pmask) == prefix)
        atomicAdd(&whist[wid][(u >> shift) & 255u], 1u);
    }
    __syncthreads();
    if (t < 256) {
      unsigned s = 0;
      for (int w = 0; w < 16; ++w) s += whist[w][t];
      chist[t] = s;
    }
    __syncthreads();
    if (t < 64) {  // wave-0 scan over 256 bins (4 per lane)
      int base = t * 4;
      unsigned ls = chist[base] + chist[base + 1] + chist[base + 2] + chist[base + 3];
      unsigned incl = ls;
      for (int off = 1; off < 64; off <<= 1) {
        unsigned v = __shfl_up(incl, off);
        if (t >= off) incl += v;
      }
      unsigned excl = incl - ls;
      if ((int)excl < rank && rank <= (int)incl) {
        unsigned c = excl;
        int binf = base;
        for (int k2 = 0; k2 < 4; ++k2) {
          unsigned h = chist[base + k2];
          if ((int)(c + h) >= rank) { binf = base + k2; break; }
          c += h;
        }
        s_bin = (unsigned)binf;
        s_cum = c;
      }
    }
    __syncthreads();
    rank -= (int)s_cum;
    prefix |= (s_bin & 255u) << shift;
    pmask |= 255u << shift;
  }
  unsigned usel = prefix;
  if (t == 0) { s_cntlt = 0; s_cnteq = 0; }
  __syncthreads();
#pragma unroll
  for (int i = 0; i < 32; ++i) {
    unsigned u = kk[i];
    int p = i * 1024 + t;
    if (u < usel) {
      unsigned pos = atomicAdd(&s_cntlt, 1u);  // total < 64 by construction
      candU[pos] = u; candI[pos] = p;
    } else if (u == usel) {
      unsigned pos = atomicAdd(&s_cnteq, 1u);
      if (pos < 192u) eqI_[pos] = p;
    }
  }
  __syncthreads();
  if (t == 0) {
    int cl = (int)s_cntlt;
    int ne = (int)s_cnteq; if (ne > 192) ne = 192;
    int need = 64 - cl;
    for (int n = 0; n < need; ++n) {  // stable ties: lowest index first
      int bmin = 0x7fffffff, bk2 = -1;
      for (int k2 = 0; k2 < ne; ++k2)
        if (eqI_[k2] < bmin) { bmin = eqI_[k2]; bk2 = k2; }
      candU[cl + n] = usel; candI[cl + n] = bmin;
      if (bk2 >= 0) eqI_[bk2] = 0x7fffffff;
    }
  }
  __syncthreads();
  if (t < 64) {  // stable (key, idx) rank-sort — canonical top_k order
    unsigned mu = candU[t];
    int mi = candI[t];
    int r = 0;
    for (int k2 = 0; k2 < 64; ++k2) {
      unsigned ou = candU[k2]; int oi = candI[k2];
      if (ou < mu || (ou == mu && oi < mi)) ++r;
    }
    float* o = ptsc + ((size_t)bg * 64 + r) * 3;
    o[0] = P[mi * 3]; o[1] = P[mi * 3 + 1]; o[2] = P[mi * 3 + 2];
  }
}

// ---- K6: patch normalize + S2PF + rescale + resample — all f32 BLAS-style --
__device__ inline float wmaxf(float v) {
  for (int off = 1; off < 64; off <<= 1) v = fmaxf(v, __shfl_xor(v, off));
  return v;
}
__device__ inline float wminf(float v) {
  for (int off = 1; off < 64; off <<= 1) v = fminf(v, __shfl_xor(v, off));
  return v;
}

__global__ __launch_bounds__(64) void k_patch(const float* __restrict__ ptsc,
                                              const float* __restrict__ se_w1,
                                              const float* __restrict__ se_b1,
                                              const float* __restrict__ sd_w1,
                                              const float* __restrict__ sd_b1,
                                              const float* __restrict__ sd_w2,
                                              const float* __restrict__ sd_b2,
                                              float* __restrict__ out) {
  int bg = blockIdx.x;
  int b = bg >> 8, g = bg & 255;
  int j = threadIdx.x;
  __shared__ float pc[64][3];
  __shared__ float xn[64][3];
  __shared__ float code[128];
  __shared__ float cmean[3];
  __shared__ float earr[64][2];
  const float* src = ptsc + ((size_t)bg * 64 + j) * 3;
  float p0 = src[0], p1 = src[1], p2 = src[2];
  pc[j][0] = p0; pc[j][1] = p1; pc[j][2] = p2;
  __syncthreads();
  // np.mean over STRIDED axis: plain SEQUENTIAL accumulation k=0..63
  if (j < 3) {
    float sum = pc[0][j];
    for (int k = 1; k < 64; ++k) sum = __fadd_rn(sum, pc[k][j]);
    cmean[j] = __fdiv_rn(sum, 64.0f);
  }
  __syncthreads();
  float x0 = __fsub_rn(p0, cmean[0]);
  float x1 = __fsub_rn(p1, cmean[1]);
  float x2 = __fsub_rn(p2, cmean[2]);
  float nr = sqrtf(__fadd_rn(__fadd_rn(__fmul_rn(x0, x0), __fmul_rn(x1, x1)),
                             __fmul_rn(x2, x2)));
  float s = wmaxf(nr);
  float den = __fadd_rn(s, 1e-8f);
  x0 = __fdiv_rn(x0, den);
  x1 = __fdiv_rn(x1, den);
  x2 = __fdiv_rn(x2, den);
  xn[j][0] = x0; xn[j][1] = x1; xn[j][2] = x2;
  __syncthreads();
  // per-point encoder (K=3 seq FMA) + relu + maxpool; 4 partial max chains
  for (int ff = 0; ff < 2; ++ff) {
    int f = j + ff * 64;
    float w0 = se_w1[0 * 128 + f];
    float w1v = se_w1[1 * 128 + f];
    float w2v = se_w1[2 * 128 + f];
    float bb = se_b1[f];
    float m0 = -__builtin_inff(), m1 = -__builtin_inff();
    float m2 = -__builtin_inff(), m3 = -__builtin_inff();
    for (int p = 0; p < 64; p += 4) {
      float a0 = fmaf(xn[p + 0][2], w2v, fmaf(xn[p + 0][1], w1v, __fmul_rn(xn[p + 0][0], w0)));
      float a1 = fmaf(xn[p + 1][2], w2v, fmaf(xn[p + 1][1], w1v, __fmul_rn(xn[p + 1][0], w0)));
      float a2 = fmaf(xn[p + 2][2], w2v, fmaf(xn[p + 2][1], w1v, __fmul_rn(xn[p + 2][0], w0)));
      float a3 = fmaf(xn[p + 3][2], w2v, fmaf(xn[p + 3][1], w1v, __fmul_rn(xn[p + 3][0], w0)));
      m0 = fmaxf(m0, fmaxf(__fadd_rn(a0, bb), 0.0f));
      m1 = fmaxf(m1, fmaxf(__fadd_rn(a1, bb), 0.0f));
      m2 = fmaxf(m2, fmaxf(__fadd_rn(a2, bb), 0.0f));
      m3 = fmaxf(m3, fmaxf(__fadd_rn(a3, bb), 0.0f));
    }
    code[f] = fmaxf(fmaxf(m0, m1), fmaxf(m2, m3));  // max assoc/comm: exact
  }
  __syncthreads();
  // sd layer1 (K=131 seq FMA per feature; 8 interleaved chains) -> relu ->
  // layer2 pe accumulated in ascending f (pinned order)
  float pe0 = 0.0f, pe1 = 0.0f;
  for (int f0 = 0; f0 < 128; f0 += 8) {
    float a[8];
#pragma unroll
    for (int u = 0; u < 8; ++u) {
      int f = f0 + u;
      float acc = __fmul_rn(x0, sd_w1[0 * 128 + f]);
      acc = fmaf(x1, sd_w1[1 * 128 + f], acc);
      a[u] = fmaf(x2, sd_w1[2 * 128 + f], acc);
    }
    for (int c = 0; c < 128; ++c) {
      float cv = code[c];
      const float* wrow = sd_w1 + (3 + c) * 128 + f0;
#pragma unroll
      for (int u = 0; u < 8; ++u) a[u] = fmaf(cv, wrow[u], a[u]);
    }
#pragma unroll
    for (int u = 0; u < 8; ++u) {
      int f = f0 + u;
      float h = fmaxf(__fadd_rn(a[u], sd_b1[f]), 0.0f);
      if (f == 0) {
        pe0 = __fmul_rn(h, sd_w2[0 * 2 + 0]);
        pe1 = __fmul_rn(h, sd_w2[0 * 2 + 1]);
      } else {
        pe0 = fmaf(h, sd_w2[f * 2 + 0], pe0);
        pe1 = fmaf(h, sd_w2[f * 2 + 1], pe1);
      }
    }
  }
  pe0 = __fadd_rn(pe0, sd_b2[0]);
  pe1 = __fadd_rn(pe1, sd_b2[1]);
  // rescale_pe, numpy elementwise op order, f32
  float mn0 = wminf(pe0), mx0 = wmaxf(pe0);
  float mn1 = wminf(pe1), mx1 = wmaxf(pe1);
  const float SPAN = (float)0.999998;
  float e0 = __fadd_rn(__fmul_rn(__fdiv_rn(__fsub_rn(pe0, mn0),
                                           __fadd_rn(__fsub_rn(mx0, mn0), 1e-8f)),
                                 SPAN), 1e-6f);
  float e1 = __fadd_rn(__fmul_rn(__fdiv_rn(__fsub_rn(pe1, mn1),
                                           __fadd_rn(__fsub_rn(mx1, mn1), 1e-8f)),
                                 SPAN), 1e-6f);
  earr[j][0] = e0;
  earr[j][1] = e1;
  __syncthreads();
  // serial per-cell argmin (np.argmin first-occurrence, f32 noFMA)
  if (j < 16) {
    float gxf = (float)((((double)(j & 3)) + 0.5) * 0.25);
    float gyf = (float)((((double)(j >> 2)) + 0.5) * 0.25);
    float best = __builtin_inff();
    int bi = 0;
    for (int sslot = 0; sslot < 64; ++sslot) {
      float dx = __fsub_rn(gxf, earr[sslot][0]);
      float dy = __fsub_rn(gyf, earr[sslot][1]);
      float d2 = __fadd_rn(__fmul_rn(dx, dx), __fmul_rn(dy, dy));
      if (d2 < best) { best = d2; bi = sslot; }
    }
    int rr = (g >> 4) * 4 + (j >> 2);
    int cc = (g & 15) * 4 + (j & 3);
    float* o = out + (((size_t)b * 4096) + (size_t)(rr * 64 + cc)) * 3;
    o[0] = pc[bi][0]; o[1] = pc[bi][1]; o[2] = pc[bi][2];
  }
}

extern "C" void kernel_launch(void* const* d_in, const int* in_sizes, int n_in,
                              void* d_out, int out_size, void* d_ws, size_t ws_size,
                              hipStream_t stream) {
  const float* pts   = (const float*)d_in[0];
  const float* ge_w1 = (const float*)d_in[1];
  const float* ge_b1 = (const float*)d_in[2];
  const float* ge_w2 = (const float*)d_in[3];
  const float* ge_b2 = (const float*)d_in[4];
  const float* gd_w1 = (const float*)d_in[5];
  const float* gd_b1 = (const float*)d_in[6];
  const float* gd_w2 = (const float*)d_in[7];
  const float* gd_b2 = (const float*)d_in[8];
  const float* se_w1 = (const float*)d_in[9];
  const float* se_b1 = (const float*)d_in[10];
  const float* sd_w1 = (const float*)d_in[11];
  const float* sd_b1 = (const float*)d_in[12];
  const float* sd_w2 = (const float*)d_in[13];
  const float* sd_b2 = (const float*)d_in[14];
  float* out = (float*)d_out;

  float* ws    = (float*)d_ws;
  float* h1    = ws;                    // 8*256*128 = 262144
  float* codeG = h1 + 262144;           // 2048
  float* recg  = codeG + 2048;          // 6144
  float* ptsg  = recg + 6144;           // 6144
  float* ptsc  = ptsg + 6144;           // 393216

  k_fps<<<NB, 1024, 0, stream>>>(pts, ptsg);
  k_enc1<<<(NB * NG * 128) / 256, 256, 0, stream>>>(ptsg, ge_w1, ge_b1, h1);
  k_code<<<NB, 1024, 0, stream>>>(h1, ge_w2, ge_b2, codeG);
  k_dec<<<NB * NG, 256, 0, stream>>>(codeG, gd_w1, gd_b1, gd_w2, gd_b2, recg);
  k_knn<<<NB * NG, 1024, 0, stream>>>(pts, recg, ptsc);
  k_patch<<<NB * NG, 64, 0, stream>>>(ptsc, se_w1, se_b1, sd_w1, sd_b1, sd_w2, sd_b2, out);
}